// Round 12
// baseline (371.392 us; speedup 1.0000x reference)
//
#include <hip/hip_runtime.h>

// Problem constants (X, Y: (64, 128, 64) fp32)
#define AA   64
#define MM   128
#define DD   64
#define CSTR 132                 // inc row stride (words); 132%32=4 -> 2-way banks (free)
#define NXY  1024                // XY gram blocks (all 4096 pairs, 4/block)
#define NTRI 544                 // triangle blocks per symmetric gram (a<=b)
#define NBLK (NXY + 2*NTRI)      // 2112
// ws layout: [0,4MB) frag regions {Xhi,Xlo,Yhi,Ylo} each 1MB; [4MB,..) partials.
#define REG_I4 65536             // int4 per 1MB region
#define PART_OFF (4u << 20)

typedef float f32x4 __attribute__((ext_vector_type(4)));
typedef short bf8_t __attribute__((ext_vector_type(8)));

template <int CTRL, int RM>
__device__ __forceinline__ float dpp0(float x) {
    return __int_as_float(
        __builtin_amdgcn_update_dpp(0, __float_as_int(x), CTRL, RM, 0xF, false));
}

__device__ __forceinline__ unsigned bf16_rne(float v) {
    unsigned u = __float_as_uint(v);
    return (u + 0x7FFFu + ((u >> 16) & 1u)) >> 16;
}
__device__ __forceinline__ float bf16_tof(unsigned h) {
    return __uint_as_float(h << 16);
}

// Fence before overwriting an inc buffer: lgkmcnt(0) guarantees all prior
// ds_reads returned (R5-verified scheme); sched_barrier stops reordering.
__device__ __forceinline__ void lds_fence() {
    asm volatile("s_waitcnt lgkmcnt(0)" ::: "memory");
    __builtin_amdgcn_sched_barrier(0);
}

// ---------------------------------------------------------------------------
// prep: build hi/lo bf16 fragments of dX/dY once, in MFMA fragment order.
// (R3/R5/R6-verified: row 127 clamped; col 127 masked in the scan.)
// ---------------------------------------------------------------------------
__global__ __launch_bounds__(256) void prep_frags(const float* __restrict__ X,
                                                  const float* __restrict__ Y,
                                                  int4* __restrict__ frag) {
    const int tid = threadIdx.x, lane = tid & 63, w = tid >> 6;
    const int W    = blockIdx.x * 4 + w;   // 0..1023
    const int inp  = W >> 9;               // 0: X, 1: Y
    const int p    = (W >> 3) & 63;
    const int tile = W & 7;
    const float* S = (inp ? Y : X) + p * (MM * DD);
    int i = tile * 16 + (lane & 15);
    if (i > 126) i = 126;
    const int d0 = (lane >> 4) << 3;

    int4* hi = frag + (inp * 2 + 0) * REG_I4;
    int4* lo = frag + (inp * 2 + 1) * REG_I4;
    const int base = p * 1024 + tile * 128 + lane;

    #pragma unroll
    for (int ks = 0; ks < 2; ++ks) {
        const float* r0 = S + i * DD + ks * 32 + d0;
        const float* r1 = r0 + DD;
        float4 a0 = *(const float4*)r0;
        float4 a1 = *(const float4*)(r0 + 4);
        float4 c0 = *(const float4*)r1;
        float4 c1 = *(const float4*)(r1 + 4);
        float v[8] = {c0.x - a0.x, c0.y - a0.y, c0.z - a0.z, c0.w - a0.w,
                      c1.x - a1.x, c1.y - a1.y, c1.z - a1.z, c1.w - a1.w};
        unsigned hs[8], ls[8];
        #pragma unroll
        for (int e = 0; e < 8; ++e) {
            hs[e] = bf16_rne(v[e]);
            ls[e] = bf16_rne(v[e] - bf16_tof(hs[e]));
        }
        int4 h, l;
        h.x = hs[0] | (hs[1] << 16); h.y = hs[2] | (hs[3] << 16);
        h.z = hs[4] | (hs[5] << 16); h.w = hs[6] | (hs[7] << 16);
        l.x = ls[0] | (ls[1] << 16); l.y = ls[2] | (ls[3] << 16);
        l.z = ls[4] | (ls[5] << 16); l.w = ls[6] | (ls[7] << 16);
        hi[base + ks * 64] = h;
        lo[base + ks * 64] = l;
    }
}

// ---------------------------------------------------------------------------
// Scan helpers -- R5/R6-verified recurrence:
//   k0 = 1 + sr1(S_prev); k1 = 1 + S_prev - e1p
//   e0 = e0p + k0*s0 ; e1 = e1p + k1*s1 (s1 masked 0 at lane 63)
//   S  = incl_scan64(e0 + e1)
// Final K[127][127] = 1 + S_prev - e1p at lane 63 after the last row.
// ---------------------------------------------------------------------------
template <int ROWS>
__device__ __forceinline__ void load_sv(const float* incW, int c2l, float2* sv) {
    #pragma unroll
    for (int r = 0; r < ROWS; ++r)
        sv[r] = *(const float2*)(incW + r * CSTR + c2l);
}

template <int ROWS>
__device__ __forceinline__ void chain_sv(const float2* sv, int lane,
                                         float& Sv, float& e0p, float& e1p) {
    #pragma unroll
    for (int r = 0; r < ROWS; ++r) {
        float s0 = sv[r].x;
        float s1 = (lane < 63) ? sv[r].y : 0.0f;
        float Sp  = dpp0<0x138, 0xF>(Sv);            // S_prev(l-1), 0 at lane0
        float k0v = 1.0f + Sp;
        float k1v = 1.0f + Sv - e1p;
        float e0  = fmaf(k0v, s0, e0p);
        float e1  = fmaf(k1v, s1, e1p);
        float S   = e0 + e1;
        S += dpp0<0x111, 0xF>(S);                    // row_shr:1
        S += dpp0<0x112, 0xF>(S);                    // row_shr:2
        S += dpp0<0x114, 0xF>(S);                    // row_shr:4
        S += dpp0<0x118, 0xF>(S);                    // row_shr:8
        S += dpp0<0x142, 0xA>(S);                    // row_bcast:15
        S += dpp0<0x143, 0xC>(S);                    // row_bcast:31
        Sv = S; e0p = e0; e1p = e1;
    }
}

// ---------------------------------------------------------------------------
// PDE kernel (v11 = the verified v5 with B fragments read DIRECTLY from
// global/L2 instead of LDS-staged). frag[] is 4 MB -> fits each XCD's L2;
// XY blocks share b 16-ways so L1 helps too. Deleting the 32 KB Bh/Bl
// staging drops LDS 50->17 KB; with 108 unified regs (76 VGPR + 32 AGPR)
// the cap becomes registers: 4 waves/SIMD -> 4 blocks/CU = 16 waves/CU
// (1.33x v5). Kernel is latency-bound (serial DS round-trip + scan chain),
// so time should scale ~inversely with residency.
// ---------------------------------------------------------------------------
__global__ __launch_bounds__(256, 4)
void sig_pde(const int4* __restrict__ frag, float* __restrict__ partials) {
    const int tid = threadIdx.x, lane = tid & 63, w = tid >> 6;
    const int gid = blockIdx.x;

    int a, b, ain, bin;
    float wgt;
    if (gid < NXY) {
        b = gid >> 4; a = ((gid & 15) << 2) | w;
        ain = 0; bin = 1;
        wgt = -2.0f / 4096.0f;
    } else {
        int t = gid - NXY;
        int inp = 0;
        if (t >= NTRI) { t -= NTRI; inp = 1; }
        int q = (int)((__builtin_sqrtf((float)(2 * t + 1)) - 1.0f) * 0.5f);
        while (2 * (q + 1) * (q + 2) <= t) ++q;
        while (q > 0 && 2 * q * (q + 1) > t) --q;
        int r  = t - 2 * q * (q + 1);
        int i  = r / (q + 1);
        int ag = r - i * (q + 1);
        b = 4 * q + i; a = 4 * ag + w;
        ain = bin = inp;
        wgt = (a < b) ? (2.0f / 4096.0f) : ((a == b) ? (1.0f / 4096.0f) : 0.0f);
    }

    __shared__ float incS[4][8 * CSTR];      // 16.9 KB per-wave 8-row buffers
    __shared__ float red4[4];

    const int4* __restrict__ Bhg = frag + (bin * 2 + 0) * REG_I4 + b * 1024;
    const int4* __restrict__ Blg = frag + (bin * 2 + 1) * REG_I4 + b * 1024;
    const int4* __restrict__ Ahg = frag + (ain * 2 + 0) * REG_I4 + a * 1024;
    const int4* __restrict__ Alg = frag + (ain * 2 + 1) * REG_I4 + a * 1024;

    int4 Ah[2], Al[2], Ahn[2], Aln[2];       // current + prefetched A frags
    f32x4 acc[8];
    float Sv = 0.0f, e0p = 0.0f, e1p = 0.0f; // scan state

    float* incW = &incS[w][0];
    const int c2l = lane << 1;
    const int r0w = (lane >> 4) << 2, c0w = lane & 15;

// 48 MFMA on the current strip (hi*hi + hi*lo + lo*hi), acc[8] = 32 AGPR.
// B fragments read straight from global (L1/L2-resident working set).
#define MFMA_STRIP() do {                                                       \
    _Pragma("unroll")                                                           \
    for (int t_ = 0; t_ < 8; ++t_) acc[t_] = (f32x4){0.f, 0.f, 0.f, 0.f};       \
    _Pragma("unroll")                                                           \
    for (int s_ = 0; s_ < 2; ++s_) {                                            \
        bf8_t ah = __builtin_bit_cast(bf8_t, Ah[s_]);                           \
        bf8_t al = __builtin_bit_cast(bf8_t, Al[s_]);                           \
        _Pragma("unroll")                                                       \
        for (int t_ = 0; t_ < 8; ++t_) {                                        \
            int fb = (t_ * 2 + s_) * 64 + lane;                                 \
            bf8_t bh = *(const bf8_t*)&Bhg[fb];                                 \
            bf8_t bl = *(const bf8_t*)&Blg[fb];                                 \
            acc[t_] = __builtin_amdgcn_mfma_f32_16x16x32_bf16(ah, bh, acc[t_], 0, 0, 0); \
            acc[t_] = __builtin_amdgcn_mfma_f32_16x16x32_bf16(ah, bl, acc[t_], 0, 0, 0); \
            acc[t_] = __builtin_amdgcn_mfma_f32_16x16x32_bf16(al, bh, acc[t_], 0, 0, 0); \
        }                                                                       \
    }                                                                           \
} while (0)

// Half-strip store: half 0 -> strip rows 0..7 (lanes r0w<8), half 1 ->
// strip rows 8..15 (lanes r0w>=8), both landing on buffer rows 0..7.
// MUST be preceded by lds_fence() (prior reads of the buffer returned).
#define STORE_H(half) do {                                     \
    if ((r0w & 8) == ((half) << 3)) {                          \
        float* pb = incW + (r0w & 7) * CSTR + c0w;             \
        _Pragma("unroll")                                      \
        for (int t_ = 0; t_ < 8; ++t_) {                       \
            float* q = pb + (t_ << 4);                         \
            q[0]        = acc[t_][0];                          \
            q[CSTR]     = acc[t_][1];                          \
            q[2 * CSTR] = acc[t_][2];                          \
            q[3 * CSTR] = acc[t_][3];                          \
        }                                                      \
    }                                                          \
} while (0)

#define LOAD_A_N(poff) do {                                    \
    int off = (poff) + lane;                                   \
    Ahn[0] = Ahg[off]; Ahn[1] = Ahg[off + 64];                 \
    Aln[0] = Alg[off]; Aln[1] = Alg[off + 64];                 \
} while (0)

    // prologue: strip 0 fragments + MFMAs
    Ah[0] = Ahg[lane]; Ah[1] = Ahg[64 + lane];
    Al[0] = Alg[lane]; Al[1] = Alg[64 + lane];
    MFMA_STRIP();                            // acc = inc strip 0

    for (int s = 0; s < 8; ++s) {
        if (s < 7) LOAD_A_N((s + 1) * 128);  // prefetch next strip's A frags

        // transpose acc -> regs via fenced 8-row buffer (R5-verified scheme)
        float2 svA[8];
        lds_fence(); STORE_H(0);
        load_sv<8>(incW, c2l, svA);
        lds_fence(); STORE_H(1);

        if (s < 7) {
            float2 svB[8];
            load_sv<8>(incW, c2l, svB);
            chain_sv<8>(svA, lane, Sv, e0p, e1p);
            Ah[0] = Ahn[0]; Ah[1] = Ahn[1];  // consume prefetch
            Al[0] = Aln[0]; Al[1] = Aln[1];
            MFMA_STRIP();                    // next strip; hides under chains
            chain_sv<8>(svB, lane, Sv, e0p, e1p);
        } else {
            float2 svB[7];                   // last strip: 8 + 7 rows
            load_sv<7>(incW, c2l, svB);
            chain_sv<8>(svA, lane, Sv, e0p, e1p);
            chain_sv<7>(svB, lane, Sv, e0p, e1p);
        }
    }

    if (lane == 63) red4[w] = wgt * (1.0f + Sv - e1p);  // weighted K[127][127]
    __syncthreads();
    if (tid == 0)
        partials[gid] = red4[0] + red4[1] + red4[2] + red4[3];

#undef MFMA_STRIP
#undef STORE_H
#undef LOAD_A_N
}

// ---------------------------------------------------------------------------
// final: out[0] = sum(partials) + mean((X0-Y0)^2). Folds the msq term with
// the 1/4096 mean weight so one reduction suffices.
// ---------------------------------------------------------------------------
__global__ void final_sum(const float* __restrict__ X, const float* __restrict__ Y,
                          const float* __restrict__ partials, float* __restrict__ out) {
    __shared__ float red[4];
    int tid = threadIdx.x;                   // 256 threads
    float acc = 0.f;
    for (int e = tid; e < NBLK; e += 256) acc += partials[e];
    for (int e = tid; e < AA * DD; e += 256) {
        int aa = e >> 6, d = e & 63;
        float df = X[aa * (MM * DD) + d] - Y[aa * (MM * DD) + d];
        acc = fmaf(df * df, 1.0f / 4096.0f, acc);
    }
    #pragma unroll
    for (int off = 32; off > 0; off >>= 1) acc += __shfl_down(acc, off);
    if ((tid & 63) == 0) red[tid >> 6] = acc;
    __syncthreads();
    if (tid == 0) out[0] = red[0] + red[1] + red[2] + red[3];
}

extern "C" void kernel_launch(void* const* d_in, const int* in_sizes, int n_in,
                              void* d_out, int out_size, void* d_ws, size_t ws_size,
                              hipStream_t stream) {
    const float* X = (const float*)d_in[0];
    const float* Y = (const float*)d_in[1];
    float* out = (float*)d_out;
    int4*  frag = (int4*)d_ws;
    float* partials = (float*)((char*)d_ws + PART_OFF);

    hipLaunchKernelGGL(prep_frags, dim3(256), dim3(256), 0, stream, X, Y, frag);
    hipLaunchKernelGGL(sig_pde, dim3(NBLK), dim3(256), 0, stream, frag, partials);
    hipLaunchKernelGGL(final_sum, dim3(1), dim3(256), 0, stream, X, Y, partials, out);
}

// Round 13
// 146.408 us; speedup vs baseline: 2.5367x; 2.5367x over previous
//
#include <hip/hip_runtime.h>

// Problem constants (X, Y: (64, 128, 64) fp32)
#define AA   64
#define MM   128
#define DD   64
#define CSTR 132                 // inc row stride (words); 132%32=4 -> 2-way banks (free)
#define NXY  1024                // XY gram blocks (all 4096 pairs, 4/block)
#define NTRI 544                 // triangle blocks per symmetric gram (a<=b)
#define NBLK (NXY + 2*NTRI)      // 2112
// ws layout: [0,4MB) frag regions {Xhi,Xlo,Yhi,Ylo} each 1MB =
//   path(64) x tile(8) x ks(2) x lane(64) x int4 ; [4MB,..) NBLK partials.
// Requires ws_size >= 4.2 MB.
#define REG_I4 65536             // int4 per 1MB region
#define PART_OFF (4u << 20)

typedef float f32x4 __attribute__((ext_vector_type(4)));
typedef short bf8_t __attribute__((ext_vector_type(8)));

template <int CTRL, int RM>
__device__ __forceinline__ float dpp0(float x) {
    return __int_as_float(
        __builtin_amdgcn_update_dpp(0, __float_as_int(x), CTRL, RM, 0xF, false));
}

__device__ __forceinline__ unsigned bf16_rne(float v) {
    unsigned u = __float_as_uint(v);
    return (u + 0x7FFFu + ((u >> 16) & 1u)) >> 16;
}
__device__ __forceinline__ float bf16_tof(unsigned h) {
    return __uint_as_float(h << 16);
}

// Fence before overwriting an inc buffer: lgkmcnt(0) guarantees all prior
// ds_reads returned (R5-verified scheme); sched_barrier stops reordering.
// Placed so the waited-on loads were already chain-consumed -> near-free.
__device__ __forceinline__ void lds_fence() {
    asm volatile("s_waitcnt lgkmcnt(0)" ::: "memory");
    __builtin_amdgcn_sched_barrier(0);
}

// ---------------------------------------------------------------------------
// prep: build hi/lo bf16 fragments of dX/dY once, in MFMA fragment order.
// A-frag and B-frag layouts coincide (idx16=lane&15, k=(lane>>4)*8+j), so one
// array serves both operand sides. Row 127 clamped to 126: as A it's the
// never-scanned row 127; as B it's col 127 whose delta is masked at lane 63.
// ---------------------------------------------------------------------------
__global__ __launch_bounds__(256) void prep_frags(const float* __restrict__ X,
                                                  const float* __restrict__ Y,
                                                  int4* __restrict__ frag) {
    const int tid = threadIdx.x, lane = tid & 63, w = tid >> 6;
    const int W    = blockIdx.x * 4 + w;   // 0..1023
    const int inp  = W >> 9;               // 0: X, 1: Y
    const int p    = (W >> 3) & 63;
    const int tile = W & 7;
    const float* S = (inp ? Y : X) + p * (MM * DD);
    int i = tile * 16 + (lane & 15);
    if (i > 126) i = 126;
    const int d0 = (lane >> 4) << 3;

    int4* hi = frag + (inp * 2 + 0) * REG_I4;
    int4* lo = frag + (inp * 2 + 1) * REG_I4;
    const int base = p * 1024 + tile * 128 + lane;

    #pragma unroll
    for (int ks = 0; ks < 2; ++ks) {
        const float* r0 = S + i * DD + ks * 32 + d0;
        const float* r1 = r0 + DD;
        float4 a0 = *(const float4*)r0;
        float4 a1 = *(const float4*)(r0 + 4);
        float4 c0 = *(const float4*)r1;
        float4 c1 = *(const float4*)(r1 + 4);
        float v[8] = {c0.x - a0.x, c0.y - a0.y, c0.z - a0.z, c0.w - a0.w,
                      c1.x - a1.x, c1.y - a1.y, c1.z - a1.z, c1.w - a1.w};
        unsigned hs[8], ls[8];
        #pragma unroll
        for (int e = 0; e < 8; ++e) {
            hs[e] = bf16_rne(v[e]);
            ls[e] = bf16_rne(v[e] - bf16_tof(hs[e]));
        }
        int4 h, l;
        h.x = hs[0] | (hs[1] << 16); h.y = hs[2] | (hs[3] << 16);
        h.z = hs[4] | (hs[5] << 16); h.w = hs[6] | (hs[7] << 16);
        l.x = ls[0] | (ls[1] << 16); l.y = ls[2] | (ls[3] << 16);
        l.z = ls[4] | (ls[5] << 16); l.w = ls[6] | (ls[7] << 16);
        hi[base + ks * 64] = h;
        lo[base + ks * 64] = l;
    }
}

// ---------------------------------------------------------------------------
// Scan helpers. Recurrence (R4/R5-verified):
//   k0 = 1 + sr1(S_prev); k1 = 1 + S_prev - e1p
//   e0 = e0p + k0*s0 ; e1 = e1p + k1*s1 (s1 masked 0 at lane 63)
//   S  = incl_scan64(e0 + e1)
// Final K[127][127] = 1 + S_prev - e1p at lane 63 after the last row.
// ---------------------------------------------------------------------------
template <int ROWS>
__device__ __forceinline__ void load_sv(const float* incW, int c2l, float2* sv) {
    #pragma unroll
    for (int r = 0; r < ROWS; ++r)
        sv[r] = *(const float2*)(incW + r * CSTR + c2l);
}

template <int ROWS>
__device__ __forceinline__ void chain_sv(const float2* sv, int lane,
                                         float& Sv, float& e0p, float& e1p) {
    #pragma unroll
    for (int r = 0; r < ROWS; ++r) {
        float s0 = sv[r].x;
        float s1 = (lane < 63) ? sv[r].y : 0.0f;
        float Sp  = dpp0<0x138, 0xF>(Sv);            // S_prev(l-1), 0 at lane0
        float k0v = 1.0f + Sp;
        float k1v = 1.0f + Sv - e1p;
        float e0  = fmaf(k0v, s0, e0p);
        float e1  = fmaf(k1v, s1, e1p);
        float S   = e0 + e1;
        S += dpp0<0x111, 0xF>(S);                    // row_shr:1
        S += dpp0<0x112, 0xF>(S);                    // row_shr:2
        S += dpp0<0x114, 0xF>(S);                    // row_shr:4
        S += dpp0<0x118, 0xF>(S);                    // row_shr:8
        S += dpp0<0x142, 0xA>(S);                    // row_bcast:15
        S += dpp0<0x143, 0xC>(S);                    // row_bcast:31
        Sv = S; e0p = e0; e1p = e1;
    }
}

// ---------------------------------------------------------------------------
// PDE kernel. gid < 1024: XY gram (all pairs). Else triangle blocks for
// XX / YY (a<=b only; weight 2 off-diag, 1 diag, 0 ragged).
// SESSION-BEST STRUCTURE (R6, 92.3 us, absmax 0): single-strip acc[8]
// (32 AGPR), 8-row fenced inc buffer (LDS 49 KB -> 3 blocks/CU), next
// strip's MFMAs issued between the two 8-row chains.
// Post-R12 note: the ~92 us wall is insensitive to occupancy (2-3 blk/CU),
// chains/wave (1-2), VALU rate (34-48%), DS clustering, B-staging location;
// all pipes <50% busy. Un-diagnosed latency serialization; needs SQ_WAIT-
// class counters to attack further.
// ---------------------------------------------------------------------------
__global__ __launch_bounds__(256, 3)
void sig_pde(const int4* __restrict__ frag, float* __restrict__ partials) {
    const int tid = threadIdx.x, lane = tid & 63, w = tid >> 6;
    const int gid = blockIdx.x;

    int a, b, ain, bin;
    float wgt;
    if (gid < NXY) {
        b = gid >> 4; a = ((gid & 15) << 2) | w;
        ain = 0; bin = 1;
        wgt = -2.0f / 4096.0f;
    } else {
        int t = gid - NXY;
        int inp = 0;
        if (t >= NTRI) { t -= NTRI; inp = 1; }
        int q = (int)((__builtin_sqrtf((float)(2 * t + 1)) - 1.0f) * 0.5f);
        while (2 * (q + 1) * (q + 2) <= t) ++q;
        while (q > 0 && 2 * q * (q + 1) > t) --q;
        int r  = t - 2 * q * (q + 1);
        int i  = r / (q + 1);
        int ag = r - i * (q + 1);
        b = 4 * q + i; a = 4 * ag + w;
        ain = bin = inp;
        wgt = (a < b) ? (2.0f / 4096.0f) : ((a == b) ? (1.0f / 4096.0f) : 0.0f);
    }

    __shared__ int4  Bh[1024], Bl[1024];     // 32 KB B fragments (hi/lo)
    __shared__ float incS[4][8 * CSTR];      // 16.9 KB per-wave 8-row buffers
    __shared__ float red4[4];

    // --- stage this block's B fragment set (flat 32 KB copy, no converts) --
    {
        const int4* Bhg = frag + (bin * 2 + 0) * REG_I4 + b * 1024;
        const int4* Blg = frag + (bin * 2 + 1) * REG_I4 + b * 1024;
        #pragma unroll
        for (int c = 0; c < 4; ++c) {
            int idx = c * 256 + tid;
            Bh[idx] = Bhg[idx];
            Bl[idx] = Blg[idx];
        }
    }
    __syncthreads();

    const int4* Ahg = frag + (ain * 2 + 0) * REG_I4 + a * 1024;
    const int4* Alg = frag + (ain * 2 + 1) * REG_I4 + a * 1024;

    int4 Ah[2], Al[2], Ahn[2], Aln[2];       // current + prefetched A frags
    f32x4 acc[8];
    float Sv = 0.0f, e0p = 0.0f, e1p = 0.0f; // scan state (K_prev row, implicit)

    float* incW = &incS[w][0];
    const int c2l = lane << 1;
    const int r0w = (lane >> 4) << 2, c0w = lane & 15;

// 48 MFMA on the current strip (hi*hi + hi*lo + lo*hi), acc[8] = 32 AGPR.
#define MFMA_STRIP() do {                                                       \
    _Pragma("unroll")                                                           \
    for (int t_ = 0; t_ < 8; ++t_) acc[t_] = (f32x4){0.f, 0.f, 0.f, 0.f};       \
    _Pragma("unroll")                                                           \
    for (int s_ = 0; s_ < 2; ++s_) {                                            \
        bf8_t ah = __builtin_bit_cast(bf8_t, Ah[s_]);                           \
        bf8_t al = __builtin_bit_cast(bf8_t, Al[s_]);                           \
        _Pragma("unroll")                                                       \
        for (int t_ = 0; t_ < 8; ++t_) {                                        \
            int fb = (t_ * 2 + s_) * 64 + lane;                                 \
            bf8_t bh = *(const bf8_t*)&Bh[fb];                                  \
            bf8_t bl = *(const bf8_t*)&Bl[fb];                                  \
            acc[t_] = __builtin_amdgcn_mfma_f32_16x16x32_bf16(ah, bh, acc[t_], 0, 0, 0); \
            acc[t_] = __builtin_amdgcn_mfma_f32_16x16x32_bf16(ah, bl, acc[t_], 0, 0, 0); \
            acc[t_] = __builtin_amdgcn_mfma_f32_16x16x32_bf16(al, bh, acc[t_], 0, 0, 0); \
        }                                                                       \
    }                                                                           \
} while (0)

// Half-strip store: half 0 -> strip rows 0..7 (lanes r0w<8), half 1 ->
// strip rows 8..15 (lanes r0w>=8), both landing on buffer rows 0..7.
// MUST be preceded by lds_fence() (prior reads of the buffer returned).
#define STORE_H(half) do {                                     \
    if ((r0w & 8) == ((half) << 3)) {                          \
        float* pb = incW + (r0w & 7) * CSTR + c0w;             \
        _Pragma("unroll")                                      \
        for (int t_ = 0; t_ < 8; ++t_) {                       \
            float* q = pb + (t_ << 4);                         \
            q[0]        = acc[t_][0];                          \
            q[CSTR]     = acc[t_][1];                          \
            q[2 * CSTR] = acc[t_][2];                          \
            q[3 * CSTR] = acc[t_][3];                          \
        }                                                      \
    }                                                          \
} while (0)

#define LOAD_A_N(poff) do {                                    \
    int off = (poff) + lane;                                   \
    Ahn[0] = Ahg[off]; Ahn[1] = Ahg[off + 64];                 \
    Aln[0] = Alg[off]; Aln[1] = Alg[off + 64];                 \
} while (0)

    // prologue: strip 0 fragments + MFMAs
    Ah[0] = Ahg[lane]; Ah[1] = Ahg[64 + lane];
    Al[0] = Alg[lane]; Al[1] = Alg[64 + lane];
    MFMA_STRIP();                            // acc = inc strip 0

    for (int s = 0; s < 8; ++s) {
        if (s < 7) LOAD_A_N((s + 1) * 128);  // prefetch next strip's A frags

        // transpose acc -> regs via fenced 8-row buffer (R5-verified scheme)
        float2 svA[8];
        lds_fence(); STORE_H(0);
        load_sv<8>(incW, c2l, svA);
        lds_fence(); STORE_H(1);

        if (s < 7) {
            float2 svB[8];
            load_sv<8>(incW, c2l, svB);
            chain_sv<8>(svA, lane, Sv, e0p, e1p);
            Ah[0] = Ahn[0]; Ah[1] = Ahn[1];  // consume prefetch
            Al[0] = Aln[0]; Al[1] = Aln[1];
            MFMA_STRIP();                    // next strip; hides under chains
            chain_sv<8>(svB, lane, Sv, e0p, e1p);
        } else {
            float2 svB[7];                   // last strip: 8 + 7 rows
            load_sv<7>(incW, c2l, svB);
            chain_sv<8>(svA, lane, Sv, e0p, e1p);
            chain_sv<7>(svB, lane, Sv, e0p, e1p);
        }
    }

    if (lane == 63) red4[w] = wgt * (1.0f + Sv - e1p);  // weighted K[127][127]
    __syncthreads();
    if (tid == 0)
        partials[gid] = red4[0] + red4[1] + red4[2] + red4[3];

#undef MFMA_STRIP
#undef STORE_H
#undef LOAD_A_N
}

// ---------------------------------------------------------------------------
// final: out[0] = sum(partials) + mean((X0-Y0)^2). Folds the msq term with
// the 1/4096 mean weight so one reduction suffices.
// ---------------------------------------------------------------------------
__global__ void final_sum(const float* __restrict__ X, const float* __restrict__ Y,
                          const float* __restrict__ partials, float* __restrict__ out) {
    __shared__ float red[4];
    int tid = threadIdx.x;                   // 256 threads
    float acc = 0.f;
    for (int e = tid; e < NBLK; e += 256) acc += partials[e];
    for (int e = tid; e < AA * DD; e += 256) {
        int aa = e >> 6, d = e & 63;
        float df = X[aa * (MM * DD) + d] - Y[aa * (MM * DD) + d];
        acc = fmaf(df * df, 1.0f / 4096.0f, acc);
    }
    #pragma unroll
    for (int off = 32; off > 0; off >>= 1) acc += __shfl_down(acc, off);
    if ((tid & 63) == 0) red[tid >> 6] = acc;
    __syncthreads();
    if (tid == 0) out[0] = red[0] + red[1] + red[2] + red[3];
}

extern "C" void kernel_launch(void* const* d_in, const int* in_sizes, int n_in,
                              void* d_out, int out_size, void* d_ws, size_t ws_size,
                              hipStream_t stream) {
    const float* X = (const float*)d_in[0];
    const float* Y = (const float*)d_in[1];
    float* out = (float*)d_out;
    int4*  frag = (int4*)d_ws;
    float* partials = (float*)((char*)d_ws + PART_OFF);

    hipLaunchKernelGGL(prep_frags, dim3(256), dim3(256), 0, stream, X, Y, frag);
    hipLaunchKernelGGL(sig_pde, dim3(NBLK), dim3(256), 0, stream, frag, partials);
    hipLaunchKernelGGL(final_sum, dim3(1), dim3(256), 0, stream, X, Y, partials, out);
}

// Round 14
// 145.377 us; speedup vs baseline: 2.5547x; 1.0071x over previous
//
#include <hip/hip_runtime.h>

// Problem constants (X, Y: (64, 128, 64) fp32)
#define AA   64
#define MM   128
#define DD   64
#define PSTR 264                 // row-PAIR stride (words): 128 cols x 2 + 8 pad
#define NXY  1024                // XY gram blocks (all 4096 pairs, 4/block)
#define NTRI 544                 // triangle blocks per symmetric gram (a<=b)
#define NBLK (NXY + 2*NTRI)      // 2112
// ws layout: [0,4MB) frag regions {Xhi,Xlo,Yhi,Ylo} each 1MB =
//   path(64) x tile(8) x ks(2) x lane(64) x int4 ; [4MB,..) NBLK partials.
#define REG_I4 65536             // int4 per 1MB region
#define PART_OFF (4u << 20)

typedef float f32x4 __attribute__((ext_vector_type(4)));
typedef short bf8_t __attribute__((ext_vector_type(8)));

template <int CTRL, int RM>
__device__ __forceinline__ float dpp0(float x) {
    return __int_as_float(
        __builtin_amdgcn_update_dpp(0, __float_as_int(x), CTRL, RM, 0xF, false));
}

__device__ __forceinline__ unsigned bf16_rne(float v) {
    unsigned u = __float_as_uint(v);
    return (u + 0x7FFFu + ((u >> 16) & 1u)) >> 16;
}
__device__ __forceinline__ float bf16_tof(unsigned h) {
    return __uint_as_float(h << 16);
}

// Fence before overwriting an inc buffer: lgkmcnt(0) guarantees all prior
// ds_reads returned (R5-verified scheme); sched_barrier stops reordering.
__device__ __forceinline__ void lds_fence() {
    asm volatile("s_waitcnt lgkmcnt(0)" ::: "memory");
    __builtin_amdgcn_sched_barrier(0);
}

// ---------------------------------------------------------------------------
// prep: build hi/lo bf16 fragments of dX/dY once, in MFMA fragment order.
// (R3/R5/R13-verified: row 127 clamped; col 127 masked in the scan.)
// ---------------------------------------------------------------------------
__global__ __launch_bounds__(256) void prep_frags(const float* __restrict__ X,
                                                  const float* __restrict__ Y,
                                                  int4* __restrict__ frag) {
    const int tid = threadIdx.x, lane = tid & 63, w = tid >> 6;
    const int W    = blockIdx.x * 4 + w;   // 0..1023
    const int inp  = W >> 9;               // 0: X, 1: Y
    const int p    = (W >> 3) & 63;
    const int tile = W & 7;
    const float* S = (inp ? Y : X) + p * (MM * DD);
    int i = tile * 16 + (lane & 15);
    if (i > 126) i = 126;
    const int d0 = (lane >> 4) << 3;

    int4* hi = frag + (inp * 2 + 0) * REG_I4;
    int4* lo = frag + (inp * 2 + 1) * REG_I4;
    const int base = p * 1024 + tile * 128 + lane;

    #pragma unroll
    for (int ks = 0; ks < 2; ++ks) {
        const float* r0 = S + i * DD + ks * 32 + d0;
        const float* r1 = r0 + DD;
        float4 a0 = *(const float4*)r0;
        float4 a1 = *(const float4*)(r0 + 4);
        float4 c0 = *(const float4*)r1;
        float4 c1 = *(const float4*)(r1 + 4);
        float v[8] = {c0.x - a0.x, c0.y - a0.y, c0.z - a0.z, c0.w - a0.w,
                      c1.x - a1.x, c1.y - a1.y, c1.z - a1.z, c1.w - a1.w};
        unsigned hs[8], ls[8];
        #pragma unroll
        for (int e = 0; e < 8; ++e) {
            hs[e] = bf16_rne(v[e]);
            ls[e] = bf16_rne(v[e] - bf16_tof(hs[e]));
        }
        int4 h, l;
        h.x = hs[0] | (hs[1] << 16); h.y = hs[2] | (hs[3] << 16);
        h.z = hs[4] | (hs[5] << 16); h.w = hs[6] | (hs[7] << 16);
        l.x = ls[0] | (ls[1] << 16); l.y = ls[2] | (ls[3] << 16);
        l.z = ls[4] | (ls[5] << 16); l.w = ls[6] | (ls[7] << 16);
        hi[base + ks * 64] = h;
        lo[base + ks * 64] = l;
    }
}

// ---------------------------------------------------------------------------
// Scan helpers -- R5/R13-verified recurrence, sourcing rows from row-PAIR
// float4 loads: pv[p] = {s0(2p), s0-odd(2p+1), s1(2p), s1(2p+1)} i.e.
// word layout (r>>1)*PSTR + 2c + (r&1):
//   row 2p  : s0 = pv[p].x, s1 = pv[p].z
//   row 2p+1: s0 = pv[p].y, s1 = pv[p].w
// Recurrence per row (unchanged):
//   k0 = 1 + sr1(S_prev); k1 = 1 + S_prev - e1p
//   e0 = e0p + k0*s0 ; e1 = e1p + k1*s1 (s1 masked 0 at lane 63)
//   S  = incl_scan64(e0 + e1)
// ---------------------------------------------------------------------------
template <int PAIRS>
__device__ __forceinline__ void load_pv(const float* buf, int l4, float4* pv) {
    #pragma unroll
    for (int p = 0; p < PAIRS; ++p)
        pv[p] = *(const float4*)(buf + p * PSTR + l4);
}

template <int ROWS>
__device__ __forceinline__ void chain_pv(const float4* pv, int lane,
                                         float& Sv, float& e0p, float& e1p) {
    #pragma unroll
    for (int r = 0; r < ROWS; ++r) {
        float s0 = (r & 1) ? pv[r >> 1].y : pv[r >> 1].x;
        float s1 = (r & 1) ? pv[r >> 1].w : pv[r >> 1].z;
        s1 = (lane < 63) ? s1 : 0.0f;
        float Sp  = dpp0<0x138, 0xF>(Sv);            // S_prev(l-1), 0 at lane0
        float k0v = 1.0f + Sp;
        float k1v = 1.0f + Sv - e1p;
        float e0  = fmaf(k0v, s0, e0p);
        float e1  = fmaf(k1v, s1, e1p);
        float S   = e0 + e1;
        S += dpp0<0x111, 0xF>(S);                    // row_shr:1
        S += dpp0<0x112, 0xF>(S);                    // row_shr:2
        S += dpp0<0x114, 0xF>(S);                    // row_shr:4
        S += dpp0<0x118, 0xF>(S);                    // row_shr:8
        S += dpp0<0x142, 0xA>(S);                    // row_bcast:15
        S += dpp0<0x143, 0xC>(S);                    // row_bcast:31
        Sv = S; e0p = e0; e1p = e1;
    }
}

// ---------------------------------------------------------------------------
// PDE kernel. v12 = R13-verified v5 skeleton with ONE change: the inc buffer
// uses a row-pair-interleaved layout addr(r,c) = (r>>1)*PSTR + 2c + (r&1).
// Effect: STORE_H's 32 scalar ds_write_b32 become 16 ds_write_b64 (acc[t][0:1]
// and [2:3] are row-adjacent -> word-adjacent), and the 8 ds_read_b64 per
// phase become 4 ds_read_b128 (a row-pair's s0/s1 for cols 2l,2l+1 is one
// aligned float4). DS ops/strip 80 -> 40, halving the VALU addressing that
// R13's accounting showed dominates VALUBusy (47% measured vs ~20% chain-only).
// Store banks: 2-way alias (free); read b128 is throughput-inherent.
// Fence discipline, recurrence, geometry, MFMA order: byte-level v5.
// ---------------------------------------------------------------------------
__global__ __launch_bounds__(256, 3)
void sig_pde(const int4* __restrict__ frag, float* __restrict__ partials) {
    const int tid = threadIdx.x, lane = tid & 63, w = tid >> 6;
    const int gid = blockIdx.x;

    int a, b, ain, bin;
    float wgt;
    if (gid < NXY) {
        b = gid >> 4; a = ((gid & 15) << 2) | w;
        ain = 0; bin = 1;
        wgt = -2.0f / 4096.0f;
    } else {
        int t = gid - NXY;
        int inp = 0;
        if (t >= NTRI) { t -= NTRI; inp = 1; }
        int q = (int)((__builtin_sqrtf((float)(2 * t + 1)) - 1.0f) * 0.5f);
        while (2 * (q + 1) * (q + 2) <= t) ++q;
        while (q > 0 && 2 * q * (q + 1) > t) --q;
        int r  = t - 2 * q * (q + 1);
        int i  = r / (q + 1);
        int ag = r - i * (q + 1);
        b = 4 * q + i; a = 4 * ag + w;
        ain = bin = inp;
        wgt = (a < b) ? (2.0f / 4096.0f) : ((a == b) ? (1.0f / 4096.0f) : 0.0f);
    }

    __shared__ int4  Bh[1024], Bl[1024];     // 32 KB B fragments (hi/lo)
    __shared__ __align__(16) float incS[4][4 * PSTR];  // 16.5 KB: 4 row-pairs
    __shared__ float red4[4];

    // --- stage this block's B fragment set (flat 32 KB copy, no converts) --
    {
        const int4* Bhg = frag + (bin * 2 + 0) * REG_I4 + b * 1024;
        const int4* Blg = frag + (bin * 2 + 1) * REG_I4 + b * 1024;
        #pragma unroll
        for (int c = 0; c < 4; ++c) {
            int idx = c * 256 + tid;
            Bh[idx] = Bhg[idx];
            Bl[idx] = Blg[idx];
        }
    }
    __syncthreads();

    const int4* Ahg = frag + (ain * 2 + 0) * REG_I4 + a * 1024;
    const int4* Alg = frag + (ain * 2 + 1) * REG_I4 + a * 1024;

    int4 Ah[2], Al[2], Ahn[2], Aln[2];       // current + prefetched A frags
    f32x4 acc[8];
    float Sv = 0.0f, e0p = 0.0f, e1p = 0.0f; // scan state

    float* incW = &incS[w][0];
    const int l4  = lane << 2;               // float4 word offset for loads
    const int r0w = (lane >> 4) << 2, c0w = lane & 15;

// 48 MFMA on the current strip (hi*hi + hi*lo + lo*hi), acc[8] = 32 AGPR.
#define MFMA_STRIP() do {                                                       \
    _Pragma("unroll")                                                           \
    for (int t_ = 0; t_ < 8; ++t_) acc[t_] = (f32x4){0.f, 0.f, 0.f, 0.f};       \
    _Pragma("unroll")                                                           \
    for (int s_ = 0; s_ < 2; ++s_) {                                            \
        bf8_t ah = __builtin_bit_cast(bf8_t, Ah[s_]);                           \
        bf8_t al = __builtin_bit_cast(bf8_t, Al[s_]);                           \
        _Pragma("unroll")                                                       \
        for (int t_ = 0; t_ < 8; ++t_) {                                        \
            int fb = (t_ * 2 + s_) * 64 + lane;                                 \
            bf8_t bh = *(const bf8_t*)&Bh[fb];                                  \
            bf8_t bl = *(const bf8_t*)&Bl[fb];                                  \
            acc[t_] = __builtin_amdgcn_mfma_f32_16x16x32_bf16(ah, bh, acc[t_], 0, 0, 0); \
            acc[t_] = __builtin_amdgcn_mfma_f32_16x16x32_bf16(ah, bl, acc[t_], 0, 0, 0); \
            acc[t_] = __builtin_amdgcn_mfma_f32_16x16x32_bf16(al, bh, acc[t_], 0, 0, 0); \
        }                                                                       \
    }                                                                           \
} while (0)

// Half-strip store, pair-interleaved: active lanes hold strip rows
// (r0w&7)+0..3 = pairs pr, pr+1 (pr = (r0w&4)>>1). acc[t][0:1] -> one
// float2 (ds_write_b64) at pair pr, acc[t][2:3] -> pair pr+1.
// MUST be preceded by lds_fence() (prior reads of the buffer returned).
#define STORE_H(half) do {                                     \
    if ((r0w & 8) == ((half) << 3)) {                          \
        float* pb = incW + ((r0w & 4) >> 1) * PSTR + (c0w << 1); \
        _Pragma("unroll")                                      \
        for (int t_ = 0; t_ < 8; ++t_) {                       \
            float2 w0 = {acc[t_][0], acc[t_][1]};              \
            float2 w1 = {acc[t_][2], acc[t_][3]};              \
            *(float2*)(pb + (t_ << 5))        = w0;            \
            *(float2*)(pb + (t_ << 5) + PSTR) = w1;            \
        }                                                      \
    }                                                          \
} while (0)

#define LOAD_A_N(poff) do {                                    \
    int off = (poff) + lane;                                   \
    Ahn[0] = Ahg[off]; Ahn[1] = Ahg[off + 64];                 \
    Aln[0] = Alg[off]; Aln[1] = Alg[off + 64];                 \
} while (0)

    // prologue: strip 0 fragments + MFMAs
    Ah[0] = Ahg[lane]; Ah[1] = Ahg[64 + lane];
    Al[0] = Alg[lane]; Al[1] = Alg[64 + lane];
    MFMA_STRIP();                            // acc = inc strip 0

    for (int s = 0; s < 8; ++s) {
        if (s < 7) LOAD_A_N((s + 1) * 128);  // prefetch next strip's A frags

        // transpose acc -> regs via fenced pair buffer (R5-verified fences)
        float4 pvA[4];
        lds_fence(); STORE_H(0);
        load_pv<4>(incW, l4, pvA);           // 4 x ds_read_b128 (rows 0-7)
        lds_fence(); STORE_H(1);

        if (s < 7) {
            float4 pvB[4];
            load_pv<4>(incW, l4, pvB);       // rows 8-15
            chain_pv<8>(pvA, lane, Sv, e0p, e1p);
            Ah[0] = Ahn[0]; Ah[1] = Ahn[1];  // consume prefetch
            Al[0] = Aln[0]; Al[1] = Aln[1];
            MFMA_STRIP();                    // next strip; hides under chains
            chain_pv<8>(pvB, lane, Sv, e0p, e1p);
        } else {
            float4 pvB[4];                   // rows 120..126 (127 stored, unused)
            load_pv<4>(incW, l4, pvB);
            chain_pv<8>(pvA, lane, Sv, e0p, e1p);
            chain_pv<7>(pvB, lane, Sv, e0p, e1p);
        }
    }

    if (lane == 63) red4[w] = wgt * (1.0f + Sv - e1p);  // weighted K[127][127]
    __syncthreads();
    if (tid == 0)
        partials[gid] = red4[0] + red4[1] + red4[2] + red4[3];

#undef MFMA_STRIP
#undef STORE_H
#undef LOAD_A_N
}

// ---------------------------------------------------------------------------
// final: out[0] = sum(partials) + mean((X0-Y0)^2). Folds the msq term with
// the 1/4096 mean weight so one reduction suffices.
// ---------------------------------------------------------------------------
__global__ void final_sum(const float* __restrict__ X, const float* __restrict__ Y,
                          const float* __restrict__ partials, float* __restrict__ out) {
    __shared__ float red[4];
    int tid = threadIdx.x;                   // 256 threads
    float acc = 0.f;
    for (int e = tid; e < NBLK; e += 256) acc += partials[e];
    for (int e = tid; e < AA * DD; e += 256) {
        int aa = e >> 6, d = e & 63;
        float df = X[aa * (MM * DD) + d] - Y[aa * (MM * DD) + d];
        acc = fmaf(df * df, 1.0f / 4096.0f, acc);
    }
    #pragma unroll
    for (int off = 32; off > 0; off >>= 1) acc += __shfl_down(acc, off);
    if ((tid & 63) == 0) red[tid >> 6] = acc;
    __syncthreads();
    if (tid == 0) out[0] = red[0] + red[1] + red[2] + red[3];
}

extern "C" void kernel_launch(void* const* d_in, const int* in_sizes, int n_in,
                              void* d_out, int out_size, void* d_ws, size_t ws_size,
                              hipStream_t stream) {
    const float* X = (const float*)d_in[0];
    const float* Y = (const float*)d_in[1];
    float* out = (float*)d_out;
    int4*  frag = (int4*)d_ws;
    float* partials = (float*)((char*)d_ws + PART_OFF);

    hipLaunchKernelGGL(prep_frags, dim3(256), dim3(256), 0, stream, X, Y, frag);
    hipLaunchKernelGGL(sig_pde, dim3(NBLK), dim3(256), 0, stream, frag, partials);
    hipLaunchKernelGGL(final_sum, dim3(1), dim3(256), 0, stream, X, Y, partials, out);
}